// Round 1
// baseline (2926.794 us; speedup 1.0000x reference)
//
#include <hip/hip_runtime.h>

// NeuralODE: B=1024, D=64, F=8, H=256, T=50, TU=128, N_SUB=4
// 196 substeps x 6 dopri5 stages, per-row-independent -> no grid sync.
// Layout: 256 blocks x 256 threads; block owns 4 batch rows.
//   phase1: thread j holds W1[:,j] in 72 VGPRs, computes h[r][j] for r=0..3
//   phase2: thread (d=tid&63, chunk=tid>>6) holds W2[chunk*64+i][d] in 64 VGPRs,
//           computes partial k[r][d] over its 64-row chunk; LDS tree-reduce.
// All LDS reads are wave-uniform float4 broadcasts (conflict-free).

__device__ __forceinline__ float fast_tanh(float x) {
    float e = __expf(2.0f * x);
    return 1.0f - 2.0f / (e + 1.0f);   // exact at +-inf saturation, ~1e-6 abs err
}

__global__ __launch_bounds__(256, 1)
void node_kernel(const float* __restrict__ x0,
                 const float* __restrict__ t_eval,
                 const float* __restrict__ t_u,
                 const float* __restrict__ u_batch,
                 const float* __restrict__ W1,
                 const float* __restrict__ b1,
                 const float* __restrict__ W2,
                 const float* __restrict__ b2,
                 float* __restrict__ out)
{
    __shared__ __align__(16) float zsh[4][72];     // [row][72] (288B rows, 16B aligned)
    __shared__ __align__(16) float hsh[4][256];    // [row][hidden]
    __shared__ __align__(16) float red[4][4][64];  // [chunk][row][d]
    __shared__ __align__(16) float ush[6][4][8];   // interpolated u per stage/row

    const int tid  = threadIdx.x;
    const int r    = tid >> 6;        // wave id = state row = phase2 j-chunk
    const int d    = tid & 63;        // state dim
    const int blk  = blockIdx.x;
    const int brow = blk * 4 + r;

    // --- weights into VGPRs (coalesced loads) ---
    float w1r[72];
#pragma unroll
    for (int i = 0; i < 72; ++i) w1r[i] = W1[i * 256 + tid];      // W1[:, tid]
    float w2r[64];
#pragma unroll
    for (int i = 0; i < 64; ++i) w2r[i] = W2[(r * 64 + i) * 64 + d]; // W2[chunk rows, d]

    const float b1j = b1[tid];
    const float b2d = b2[d];

    float x = x0[brow * 64 + d];
    out[brow * (50 * 64) + d] = x;    // t_eval[0] output

    float k1 = 0.f, k2 = 0.f, k3 = 0.f, k4 = 0.f, k5 = 0.f, k6 = 0.f;

#pragma unroll 1
    for (int step = 0; step < 196; ++step) {
        const int n = step >> 2;
        const int m = step & 3;
        const float te0 = t_eval[n];
        const float dtc = t_eval[n + 1] - te0;
        const float t   = te0 + dtc * (0.25f * (float)m);
        const float dt  = dtc * 0.25f;

        // --- prefetch+interp u for all 6 stages of this step ---
        if (tid < 192) {
            const int s  = tid >> 5;          // stage 0..5
            const int rr = (tid >> 3) & 3;    // row
            const int f  = tid & 7;           // feature
            float tsv;
            switch (s) {
                case 0: tsv = t; break;
                case 1: tsv = t + dt * (1.0f/5.0f); break;
                case 2: tsv = t + dt * (3.0f/10.0f); break;
                case 3: tsv = t + dt * (4.0f/5.0f); break;
                case 4: tsv = t + dt * (8.0f/9.0f); break;
                default: tsv = t + dt; break;
            }
            // searchsorted(t_u, t, 'right')-1 == floor(t*127) here (gap >= 4e-5 >> fp32 eps)
            int idx = (int)(tsv * 127.0f);
            idx = idx < 0 ? 0 : (idx > 126 ? 126 : idx);
            const float ta = t_u[idx];
            const float tb = t_u[idx + 1];
            const float w  = (tsv - ta) / (tb - ta);
            const int base = (blk * 4 + rr) * (128 * 8) + idx * 8 + f;
            const float u0v = u_batch[base];
            const float u1v = u_batch[base + 8];
            ush[s][rr][f] = fmaf(w, u1v - u0v, u0v);
        }
        __syncthreads();

#pragma unroll 1
        for (int s = 0; s < 6; ++s) {
            // --- stage state z = [x_s, u_s] ---
            float xs;
            switch (s) {
                case 0: xs = x; break;
                case 1: xs = fmaf(dt, k1 * (1.0f/5.0f), x); break;
                case 2: xs = fmaf(dt, fmaf(3.0f/40.0f, k1, (9.0f/40.0f)*k2), x); break;
                case 3: xs = fmaf(dt, (44.0f/45.0f)*k1 + (-56.0f/15.0f)*k2 + (32.0f/9.0f)*k3, x); break;
                case 4: xs = fmaf(dt, (19372.0f/6561.0f)*k1 + (-25360.0f/2187.0f)*k2
                                     + (64448.0f/6561.0f)*k3 + (-212.0f/729.0f)*k4, x); break;
                default: xs = fmaf(dt, (9017.0f/3168.0f)*k1 + (-355.0f/33.0f)*k2
                                      + (46732.0f/5247.0f)*k3 + (49.0f/176.0f)*k4
                                      + (-5103.0f/18656.0f)*k5, x); break;
            }
            zsh[r][d] = xs;
            if (d < 8) zsh[r][64 + d] = ush[s][r][d];
            __syncthreads();

            // --- phase 1: h[rr][tid] = tanh(z[rr] . W1[:,tid] + b1) ---
            float a0 = b1j, a1 = b1j, a2 = b1j, a3 = b1j;
#pragma unroll
            for (int i = 0; i < 72; i += 4) {
                const float4 z0 = *(const float4*)&zsh[0][i];
                const float4 z1 = *(const float4*)&zsh[1][i];
                const float4 z2 = *(const float4*)&zsh[2][i];
                const float4 z3 = *(const float4*)&zsh[3][i];
                a0 = fmaf(z0.x, w1r[i],   a0); a1 = fmaf(z1.x, w1r[i],   a1);
                a2 = fmaf(z2.x, w1r[i],   a2); a3 = fmaf(z3.x, w1r[i],   a3);
                a0 = fmaf(z0.y, w1r[i+1], a0); a1 = fmaf(z1.y, w1r[i+1], a1);
                a2 = fmaf(z2.y, w1r[i+1], a2); a3 = fmaf(z3.y, w1r[i+1], a3);
                a0 = fmaf(z0.z, w1r[i+2], a0); a1 = fmaf(z1.z, w1r[i+2], a1);
                a2 = fmaf(z2.z, w1r[i+2], a2); a3 = fmaf(z3.z, w1r[i+2], a3);
                a0 = fmaf(z0.w, w1r[i+3], a0); a1 = fmaf(z1.w, w1r[i+3], a1);
                a2 = fmaf(z2.w, w1r[i+3], a2); a3 = fmaf(z3.w, w1r[i+3], a3);
            }
            hsh[0][tid] = fast_tanh(a0);
            hsh[1][tid] = fast_tanh(a1);
            hsh[2][tid] = fast_tanh(a2);
            hsh[3][tid] = fast_tanh(a3);
            __syncthreads();

            // --- phase 2: partial k[rr][d] over this wave's 64-row W2 chunk ---
            float p0 = 0.f, p1 = 0.f, p2 = 0.f, p3 = 0.f;
            const int j0 = r * 64;
#pragma unroll
            for (int i = 0; i < 64; i += 4) {
                const float4 h0 = *(const float4*)&hsh[0][j0 + i];
                const float4 h1 = *(const float4*)&hsh[1][j0 + i];
                const float4 h2 = *(const float4*)&hsh[2][j0 + i];
                const float4 h3 = *(const float4*)&hsh[3][j0 + i];
                p0 = fmaf(h0.x, w2r[i],   p0); p1 = fmaf(h1.x, w2r[i],   p1);
                p2 = fmaf(h2.x, w2r[i],   p2); p3 = fmaf(h3.x, w2r[i],   p3);
                p0 = fmaf(h0.y, w2r[i+1], p0); p1 = fmaf(h1.y, w2r[i+1], p1);
                p2 = fmaf(h2.y, w2r[i+1], p2); p3 = fmaf(h3.y, w2r[i+1], p3);
                p0 = fmaf(h0.z, w2r[i+2], p0); p1 = fmaf(h1.z, w2r[i+2], p1);
                p2 = fmaf(h2.z, w2r[i+2], p2); p3 = fmaf(h3.z, w2r[i+2], p3);
                p0 = fmaf(h0.w, w2r[i+3], p0); p1 = fmaf(h1.w, w2r[i+3], p1);
                p2 = fmaf(h2.w, w2r[i+3], p2); p3 = fmaf(h3.w, w2r[i+3], p3);
            }
            red[r][0][d] = p0;
            red[r][1][d] = p1;
            red[r][2][d] = p2;
            red[r][3][d] = p3;
            __syncthreads();

            const float kv = b2d + ((red[0][r][d] + red[1][r][d]) + (red[2][r][d] + red[3][r][d]));
            switch (s) {
                case 0: k1 = kv; break;
                case 1: k2 = kv; break;
                case 2: k3 = kv; break;
                case 3: k4 = kv; break;
                case 4: k5 = kv; break;
                default: k6 = kv; break;
            }
        }

        // --- dopri5 update ---
        x = fmaf(dt, (35.0f/384.0f)*k1 + (500.0f/1113.0f)*k3 + (125.0f/192.0f)*k4
                    + (-2187.0f/6784.0f)*k5 + (11.0f/84.0f)*k6, x);
        if (m == 3) out[brow * (50 * 64) + (n + 1) * 64 + d] = x;
    }
}

extern "C" void kernel_launch(void* const* d_in, const int* in_sizes, int n_in,
                              void* d_out, int out_size, void* d_ws, size_t ws_size,
                              hipStream_t stream) {
    const float* x0      = (const float*)d_in[0];
    const float* t_eval  = (const float*)d_in[1];
    const float* t_u     = (const float*)d_in[2];
    const float* u_batch = (const float*)d_in[3];
    const float* W1      = (const float*)d_in[4];
    const float* b1      = (const float*)d_in[5];
    const float* W2      = (const float*)d_in[6];
    const float* b2      = (const float*)d_in[7];
    float* out = (float*)d_out;

    node_kernel<<<dim3(256), dim3(256), 0, stream>>>(
        x0, t_eval, t_u, u_batch, W1, b1, W2, b2, out);
}

// Round 2
// 2163.286 us; speedup vs baseline: 1.3529x; 1.3529x over previous
//
#include <hip/hip_runtime.h>

// NeuralODE: B=1024, D=64, F=8, H=256, 196 substeps x 6 dopri5 stages.
// R2: 512 blocks x 256 threads, 2 batch rows/block -> 2 blocks/CU (8 waves).
// Weights pinned in VGPRs via asm barrier (R1: compiler sank them, VGPR=96).
// C=2 column blocking in both phases: each LDS float4 read feeds 8 FMAs.
//   phase1: thread owns W1 cols (c0, c0+128) [144 VGPR], computes its row rw.
//   phase2: thread owns W2[g*32..g*32+31][d0, d0+32] [64 VGPR], both rows.
// Waves 0,2 own the ODE state (row 0,1); odd waves idle in staging/reduce.

__device__ __forceinline__ float fast_tanh(float x) {
    float e = __expf(2.0f * x);
    return 1.0f - 2.0f / (e + 1.0f);   // saturates correctly, ~1e-6 abs err
}

__global__ __launch_bounds__(256, 2)
void node_kernel(const float* __restrict__ x0,
                 const float* __restrict__ t_eval,
                 const float* __restrict__ t_u,
                 const float* __restrict__ u_batch,
                 const float* __restrict__ W1,
                 const float* __restrict__ b1,
                 const float* __restrict__ W2,
                 const float* __restrict__ b2,
                 float* __restrict__ out)
{
    __shared__ __align__(16) float zsh[2][72];      // [row][D+F]
    __shared__ __align__(16) float hsh[2][256];     // [row][hidden]
    __shared__ __align__(16) float red[2][64][9];   // [row][d][chunk], pad 9: conflict-free
    __shared__ __align__(16) float ush[6][2][8];    // interp u per stage/row

    const int tid = threadIdx.x;
    const int w   = tid >> 6;
    const int rw  = tid >> 7;           // this thread's batch row (0/1)
    const int d   = tid & 63;
    const bool owner = (w & 1) == 0;    // waves 0,2 carry state x,k
    const int blk = blockIdx.x;

    // --- weights into VGPRs ---
    const int c0 = tid & 127;           // phase1 columns c0 and c0+128
    float w1a[72], w1b[72];
#pragma unroll
    for (int i = 0; i < 72; ++i) {
        w1a[i] = W1[i * 256 + c0];
        w1b[i] = W1[i * 256 + c0 + 128];
    }
    const int d0 = tid & 31;            // phase2 output cols d0, d0+32
    const int g  = tid >> 5;            // phase2 j-chunk 0..7
    float w2a[32], w2b[32];
#pragma unroll
    for (int j = 0; j < 32; ++j) {
        w2a[j] = W2[(g * 32 + j) * 64 + d0];
        w2b[j] = W2[(g * 32 + j) * 64 + d0 + 32];
    }
    // pin: asm output can't be rematerialized -> loads can't be sunk into loop
#pragma unroll
    for (int i = 0; i < 72; ++i) { asm volatile("" : "+v"(w1a[i])); asm volatile("" : "+v"(w1b[i])); }
#pragma unroll
    for (int j = 0; j < 32; ++j) { asm volatile("" : "+v"(w2a[j])); asm volatile("" : "+v"(w2b[j])); }

    const float b1c0 = b1[c0];
    const float b1c1 = b1[c0 + 128];
    const float b2d  = b2[d];

    float x = 0.f;
    if (owner) {
        x = x0[(blk * 2 + rw) * 64 + d];
        out[(blk * 2 + rw) * 3200 + d] = x;     // t_eval[0]
    }
    float k1 = 0.f, k2 = 0.f, k3 = 0.f, k4 = 0.f, k5 = 0.f, k6 = 0.f;

#pragma unroll 1
    for (int step = 0; step < 196; ++step) {
        const int n = step >> 2;
        const int m = step & 3;
        const float te0 = t_eval[n];
        const float dtc = t_eval[n + 1] - te0;
        const float t   = te0 + dtc * (0.25f * (float)m);
        const float dt  = dtc * 0.25f;

        // --- prefetch+interp u for all 6 stages of this step ---
        if (tid < 96) {
            const int s  = tid >> 4;
            const int rr = (tid >> 3) & 1;
            const int f  = tid & 7;
            float tsv;
            switch (s) {
                case 0: tsv = t; break;
                case 1: tsv = t + dt * (1.0f/5.0f); break;
                case 2: tsv = t + dt * (3.0f/10.0f); break;
                case 3: tsv = t + dt * (4.0f/5.0f); break;
                case 4: tsv = t + dt * (8.0f/9.0f); break;
                default: tsv = t + dt; break;
            }
            int idx = (int)(tsv * 127.0f);      // == searchsorted-1 (gap >= 4e-5)
            idx = idx < 0 ? 0 : (idx > 126 ? 126 : idx);
            const float ta = t_u[idx];
            const float tb = t_u[idx + 1];
            const float wt = (tsv - ta) / (tb - ta);
            const int base = (blk * 2 + rr) * (128 * 8) + idx * 8 + f;
            const float u0v = u_batch[base];
            const float u1v = u_batch[base + 8];
            ush[s][rr][f] = fmaf(wt, u1v - u0v, u0v);
        }
        __syncthreads();

#pragma unroll 1
        for (int s = 0; s < 6; ++s) {
            // --- staging: owner waves write z = [x_s, u_s] for their row ---
            if (owner) {
                float xs;
                switch (s) {
                    case 0: xs = x; break;
                    case 1: xs = fmaf(dt, k1 * (1.0f/5.0f), x); break;
                    case 2: xs = fmaf(dt, fmaf(3.0f/40.0f, k1, (9.0f/40.0f)*k2), x); break;
                    case 3: xs = fmaf(dt, (44.0f/45.0f)*k1 + (-56.0f/15.0f)*k2 + (32.0f/9.0f)*k3, x); break;
                    case 4: xs = fmaf(dt, (19372.0f/6561.0f)*k1 + (-25360.0f/2187.0f)*k2
                                         + (64448.0f/6561.0f)*k3 + (-212.0f/729.0f)*k4, x); break;
                    default: xs = fmaf(dt, (9017.0f/3168.0f)*k1 + (-355.0f/33.0f)*k2
                                          + (46732.0f/5247.0f)*k3 + (49.0f/176.0f)*k4
                                          + (-5103.0f/18656.0f)*k5, x); break;
                }
                zsh[rw][d] = xs;
                if (d < 8) zsh[rw][64 + d] = ush[s][rw][d];
            }
            __syncthreads();

            // --- phase 1: h[rw][c0], h[rw][c0+128] (each z read feeds 8 FMAs) ---
            float a0 = b1c0, a1 = b1c1;
#pragma unroll
            for (int i = 0; i < 72; i += 4) {
                const float4 z = *(const float4*)&zsh[rw][i];
                a0 = fmaf(z.x, w1a[i],   a0);  a1 = fmaf(z.x, w1b[i],   a1);
                a0 = fmaf(z.y, w1a[i+1], a0);  a1 = fmaf(z.y, w1b[i+1], a1);
                a0 = fmaf(z.z, w1a[i+2], a0);  a1 = fmaf(z.z, w1b[i+2], a1);
                a0 = fmaf(z.w, w1a[i+3], a0);  a1 = fmaf(z.w, w1b[i+3], a1);
            }
            hsh[rw][c0]       = fast_tanh(a0);
            hsh[rw][c0 + 128] = fast_tanh(a1);
            __syncthreads();

            // --- phase 2: partials for (row 0/1) x (d0, d0+32) over 32-j chunk ---
            float p00 = 0.f, p01 = 0.f, p10 = 0.f, p11 = 0.f;
            const int jb = g * 32;
#pragma unroll
            for (int i = 0; i < 32; i += 4) {
                const float4 h0 = *(const float4*)&hsh[0][jb + i];
                const float4 h1 = *(const float4*)&hsh[1][jb + i];
                p00 = fmaf(h0.x, w2a[i],   p00);  p01 = fmaf(h0.x, w2b[i],   p01);
                p10 = fmaf(h1.x, w2a[i],   p10);  p11 = fmaf(h1.x, w2b[i],   p11);
                p00 = fmaf(h0.y, w2a[i+1], p00);  p01 = fmaf(h0.y, w2b[i+1], p01);
                p10 = fmaf(h1.y, w2a[i+1], p10);  p11 = fmaf(h1.y, w2b[i+1], p11);
                p00 = fmaf(h0.z, w2a[i+2], p00);  p01 = fmaf(h0.z, w2b[i+2], p01);
                p10 = fmaf(h1.z, w2a[i+2], p10);  p11 = fmaf(h1.z, w2b[i+2], p11);
                p00 = fmaf(h0.w, w2a[i+3], p00);  p01 = fmaf(h0.w, w2b[i+3], p01);
                p10 = fmaf(h1.w, w2a[i+3], p10);  p11 = fmaf(h1.w, w2b[i+3], p11);
            }
            red[0][d0][g]      = p00;
            red[0][d0 + 32][g] = p01;
            red[1][d0][g]      = p10;
            red[1][d0 + 32][g] = p11;
            __syncthreads();

            // --- reduce 8 chunks -> k (owner waves only) ---
            if (owner) {
                const float* rp = red[rw][d];
                const float kv = b2d + (((rp[0] + rp[1]) + (rp[2] + rp[3]))
                                      + ((rp[4] + rp[5]) + (rp[6] + rp[7])));
                switch (s) {
                    case 0: k1 = kv; break;
                    case 1: k2 = kv; break;
                    case 2: k3 = kv; break;
                    case 3: k4 = kv; break;
                    case 4: k5 = kv; break;
                    default: k6 = kv; break;
                }
            }
        }

        // --- dopri5 update ---
        if (owner) {
            x = fmaf(dt, (35.0f/384.0f)*k1 + (500.0f/1113.0f)*k3 + (125.0f/192.0f)*k4
                        + (-2187.0f/6784.0f)*k5 + (11.0f/84.0f)*k6, x);
            if (m == 3) out[(blk * 2 + rw) * 3200 + (n + 1) * 64 + d] = x;
        }
    }
}

extern "C" void kernel_launch(void* const* d_in, const int* in_sizes, int n_in,
                              void* d_out, int out_size, void* d_ws, size_t ws_size,
                              hipStream_t stream) {
    const float* x0      = (const float*)d_in[0];
    const float* t_eval  = (const float*)d_in[1];
    const float* t_u     = (const float*)d_in[2];
    const float* u_batch = (const float*)d_in[3];
    const float* W1      = (const float*)d_in[4];
    const float* b1      = (const float*)d_in[5];
    const float* W2      = (const float*)d_in[6];
    const float* b2      = (const float*)d_in[7];
    float* out = (float*)d_out;

    node_kernel<<<dim3(512), dim3(256), 0, stream>>>(
        x0, t_eval, t_u, u_batch, W1, b1, W2, b2, out);
}

// Round 3
// 1991.955 us; speedup vs baseline: 1.4693x; 1.0860x over previous
//
#include <hip/hip_runtime.h>

// NeuralODE: B=1024, D=64, F=8, H=256, 196 substeps x 6 dopri5 stages.
// R3: 512 blocks x 256 threads x 2 rows/block, 2 blocks/CU (launch_bounds(256,2)).
// Per-thread weight set cut to the per-block minimum 136 floats (R2's 208 put
// total pressure at the 256-VGPR cap -> allocator spilled to AGPRs, costing
// ~200 v_accvgpr_read/thread/stage; VGPR_Count=128 was the tell).
//   phase1: thread owns W1[:,tid]   (72 VGPR), computes h[row][tid] for both rows
//   phase2: thread (d=tid&63,g=wave) owns W2[g*64..+63][d] (64 VGPR), both rows
// Waves 0,1 carry ODE state for rows 0,1 (wave-uniform gating = free).
// All hot LDS reads are wave-uniform float4 broadcasts; red[] stride-5 b32
// (5 coprime 32 -> 2-way aliasing only, free per m136).

__device__ __forceinline__ float fast_tanh(float x) {
    float e = __expf(2.0f * x);
    return 1.0f - 2.0f / (e + 1.0f);   // saturates correctly, ~1e-6 abs err
}

__global__ __launch_bounds__(256, 2)
void node_kernel(const float* __restrict__ x0,
                 const float* __restrict__ t_eval,
                 const float* __restrict__ t_u,
                 const float* __restrict__ u_batch,
                 const float* __restrict__ W1,
                 const float* __restrict__ b1,
                 const float* __restrict__ W2,
                 const float* __restrict__ b2,
                 float* __restrict__ out)
{
    __shared__ __align__(16) float zsh[2][72];     // [row][D+F]
    __shared__ __align__(16) float hsh[2][256];    // [row][hidden]
    __shared__ __align__(16) float red[2][64][5];  // [row][d][chunk], stride 5
    __shared__ __align__(16) float ush[6][2][8];   // interp u per stage/row

    const int tid = threadIdx.x;
    const int w   = tid >> 6;           // wave id; phase2 j-chunk; state row if <2
    const int l   = tid & 63;           // lane; phase2 d; state dim
    const int blk = blockIdx.x;

    // --- weights into VGPRs (coalesced) ---
    float w1r[72];
#pragma unroll
    for (int i = 0; i < 72; ++i) w1r[i] = W1[i * 256 + tid];          // W1[:, tid]
    float w2r[64];
#pragma unroll
    for (int j = 0; j < 64; ++j) w2r[j] = W2[(w * 64 + j) * 64 + l];  // W2 chunk, col l
    // pin: asm outputs can't be rematerialized -> loads can't be sunk into loop
#pragma unroll
    for (int i = 0; i < 72; ++i) asm volatile("" : "+v"(w1r[i]));
#pragma unroll
    for (int j = 0; j < 64; ++j) asm volatile("" : "+v"(w2r[j]));

    const float b1c = b1[tid];
    const float b2d = b2[l];

    // ODE state: wave 0 -> row 0, wave 1 -> row 1 (lane l holds dim l)
    float x = 0.f;
    if (w < 2) {
        x = x0[(blk * 2 + w) * 64 + l];
        out[(blk * 2 + w) * 3200 + l] = x;     // t_eval[0]
    }
    float k1 = 0.f, k2 = 0.f, k3 = 0.f, k4 = 0.f, k5 = 0.f, k6 = 0.f;

#pragma unroll 1
    for (int step = 0; step < 196; ++step) {
        const int n = step >> 2;
        const int m = step & 3;
        const float te0 = t_eval[n];
        const float dtc = t_eval[n + 1] - te0;
        const float t   = te0 + dtc * (0.25f * (float)m);
        const float dt  = dtc * 0.25f;

        // --- prefetch+interp u for all 6 stages of this step ---
        if (tid < 96) {
            const int s  = tid >> 4;
            const int rr = (tid >> 3) & 1;
            const int f  = tid & 7;
            float tsv;
            switch (s) {
                case 0: tsv = t; break;
                case 1: tsv = t + dt * (1.0f/5.0f); break;
                case 2: tsv = t + dt * (3.0f/10.0f); break;
                case 3: tsv = t + dt * (4.0f/5.0f); break;
                case 4: tsv = t + dt * (8.0f/9.0f); break;
                default: tsv = t + dt; break;
            }
            int idx = (int)(tsv * 127.0f);      // == searchsorted-1 (gap >= 4e-5)
            idx = idx < 0 ? 0 : (idx > 126 ? 126 : idx);
            const float ta = t_u[idx];
            const float tb = t_u[idx + 1];
            const float wt = (tsv - ta) / (tb - ta);
            const int base = (blk * 2 + rr) * (128 * 8) + idx * 8 + f;
            const float u0v = u_batch[base];
            const float u1v = u_batch[base + 8];
            ush[s][rr][f] = fmaf(wt, u1v - u0v, u0v);
        }
        __syncthreads();

#pragma unroll 1
        for (int s = 0; s < 6; ++s) {
            // --- staging: waves 0,1 publish z = [x_s, u_s] for their row ---
            if (w < 2) {
                float xs;
                switch (s) {
                    case 0: xs = x; break;
                    case 1: xs = fmaf(dt, k1 * (1.0f/5.0f), x); break;
                    case 2: xs = fmaf(dt, fmaf(3.0f/40.0f, k1, (9.0f/40.0f)*k2), x); break;
                    case 3: xs = fmaf(dt, (44.0f/45.0f)*k1 + (-56.0f/15.0f)*k2 + (32.0f/9.0f)*k3, x); break;
                    case 4: xs = fmaf(dt, (19372.0f/6561.0f)*k1 + (-25360.0f/2187.0f)*k2
                                         + (64448.0f/6561.0f)*k3 + (-212.0f/729.0f)*k4, x); break;
                    default: xs = fmaf(dt, (9017.0f/3168.0f)*k1 + (-355.0f/33.0f)*k2
                                          + (46732.0f/5247.0f)*k3 + (49.0f/176.0f)*k4
                                          + (-5103.0f/18656.0f)*k5, x); break;
                }
                zsh[w][l] = xs;
                if (l < 8) zsh[w][64 + l] = ush[s][w][l];
            }
            __syncthreads();

            // --- phase 1: h[r][tid] = tanh(z[r] . W1[:,tid] + b1), both rows ---
            float a0 = b1c, a1 = b1c;
#pragma unroll
            for (int i = 0; i < 72; i += 4) {
                const float4 z0 = *(const float4*)&zsh[0][i];
                const float4 z1 = *(const float4*)&zsh[1][i];
                a0 = fmaf(z0.x, w1r[i],   a0);  a1 = fmaf(z1.x, w1r[i],   a1);
                a0 = fmaf(z0.y, w1r[i+1], a0);  a1 = fmaf(z1.y, w1r[i+1], a1);
                a0 = fmaf(z0.z, w1r[i+2], a0);  a1 = fmaf(z1.z, w1r[i+2], a1);
                a0 = fmaf(z0.w, w1r[i+3], a0);  a1 = fmaf(z1.w, w1r[i+3], a1);
            }
            hsh[0][tid] = fast_tanh(a0);
            hsh[1][tid] = fast_tanh(a1);
            __syncthreads();

            // --- phase 2: partials over this wave's 64-j W2 chunk, both rows ---
            float p0 = 0.f, p1 = 0.f;
            const int jb = w * 64;
#pragma unroll
            for (int j = 0; j < 64; j += 4) {
                const float4 h0 = *(const float4*)&hsh[0][jb + j];
                const float4 h1 = *(const float4*)&hsh[1][jb + j];
                p0 = fmaf(h0.x, w2r[j],   p0);  p1 = fmaf(h1.x, w2r[j],   p1);
                p0 = fmaf(h0.y, w2r[j+1], p0);  p1 = fmaf(h1.y, w2r[j+1], p1);
                p0 = fmaf(h0.z, w2r[j+2], p0);  p1 = fmaf(h1.z, w2r[j+2], p1);
                p0 = fmaf(h0.w, w2r[j+3], p0);  p1 = fmaf(h1.w, w2r[j+3], p1);
            }
            red[0][l][w] = p0;
            red[1][l][w] = p1;
            __syncthreads();

            // --- reduce 4 chunks -> k (state waves only) ---
            if (w < 2) {
                const float* rp = red[w][l];
                const float kv = b2d + ((rp[0] + rp[1]) + (rp[2] + rp[3]));
                switch (s) {
                    case 0: k1 = kv; break;
                    case 1: k2 = kv; break;
                    case 2: k3 = kv; break;
                    case 3: k4 = kv; break;
                    case 4: k5 = kv; break;
                    default: k6 = kv; break;
                }
            }
        }

        // --- dopri5 update ---
        if (w < 2) {
            x = fmaf(dt, (35.0f/384.0f)*k1 + (500.0f/1113.0f)*k3 + (125.0f/192.0f)*k4
                        + (-2187.0f/6784.0f)*k5 + (11.0f/84.0f)*k6, x);
            if (m == 3) out[(blk * 2 + w) * 3200 + (n + 1) * 64 + l] = x;
        }
    }
}

extern "C" void kernel_launch(void* const* d_in, const int* in_sizes, int n_in,
                              void* d_out, int out_size, void* d_ws, size_t ws_size,
                              hipStream_t stream) {
    const float* x0      = (const float*)d_in[0];
    const float* t_eval  = (const float*)d_in[1];
    const float* t_u     = (const float*)d_in[2];
    const float* u_batch = (const float*)d_in[3];
    const float* W1      = (const float*)d_in[4];
    const float* b1      = (const float*)d_in[5];
    const float* W2      = (const float*)d_in[6];
    const float* b2      = (const float*)d_in[7];
    float* out = (float*)d_out;

    node_kernel<<<dim3(512), dim3(256), 0, stream>>>(
        x0, t_eval, t_u, u_batch, W1, b1, W2, b2, out);
}